// Round 1
// baseline (101.955 us; speedup 1.0000x reference)
//
#include <hip/hip_runtime.h>
#include <hip/hip_bf16.h>

// out[g][c] = sum_{w=0..19} x[g*20 + w][c] * y[g*20 + w]
// x: [N,64] f32, y: [N] f32, out: [N/20, 64] f32.
// Thread layout: 16 threads per group, each owns a float4 (4 channels).
// Consecutive threads -> consecutive 16B chunks of one x row: fully coalesced.

#define WINDOW 20
#define C4 16  // 64 channels / 4 per float4

__global__ void Pool_46763603919352_kernel(const float* __restrict__ x,
                                           const float* __restrict__ y,
                                           float* __restrict__ out,
                                           int G) {
    int tid = blockIdx.x * blockDim.x + threadIdx.x;
    int total = G * C4;
    if (tid >= total) return;

    int g  = tid >> 4;        // group index
    int c4 = tid & (C4 - 1);  // which float4 within the 64-channel row

    const float4* xg = reinterpret_cast<const float4*>(x)
                       + (size_t)g * WINDOW * C4 + c4;
    const float* yg = y + (size_t)g * WINDOW;

    float4 acc = make_float4(0.f, 0.f, 0.f, 0.f);
#pragma unroll
    for (int w = 0; w < WINDOW; ++w) {
        float4 v = xg[(size_t)w * C4];
        float  s = yg[w];
        acc.x += v.x * s;
        acc.y += v.y * s;
        acc.z += v.z * s;
        acc.w += v.w * s;
    }
    reinterpret_cast<float4*>(out)[tid] = acc;
}

extern "C" void kernel_launch(void* const* d_in, const int* in_sizes, int n_in,
                              void* d_out, int out_size, void* d_ws, size_t ws_size,
                              hipStream_t stream) {
    const float* x = (const float*)d_in[0];
    const float* y = (const float*)d_in[1];
    // d_in[2] = batch (unused on fla==0 path), d_in[3] = fla (always 0 here)
    float* out = (float*)d_out;

    int N = in_sizes[1];        // y has N elements
    int G = N / WINDOW;         // number of output rows

    int total   = G * C4;      // one thread per output float4
    int block   = 256;
    int grid    = (total + block - 1) / block;
    Pool_46763603919352_kernel<<<grid, block, 0, stream>>>(x, y, out, G);
}

// Round 3
// 88.102 us; speedup vs baseline: 1.1572x; 1.1572x over previous
//
#include <hip/hip_runtime.h>
#include <hip/hip_bf16.h>

// out[g][c] = sum_{w=0..19} x[g*20 + w][c] * y[g*20 + w]
// x: [N,64] f32, y: [N] f32, out: [N/20, 64] f32.
// Thread layout: 16 threads per group, each owns a float4 (4 channels).
// 16 consecutive lanes read one contiguous 256B row of x; a wave covers 4
// adjacent groups (4 contiguous 5KB blocks) -> fully sequential stream.
// x (512MB, zero reuse, > 256MB L3) and out are non-temporal to avoid
// cache thrash; y (8MB, lane-broadcast) stays on the cached path.
// NOTE: __builtin_nontemporal_* requires native vector types, not
// HIP_vector_type structs -> use clang ext_vector_type.

#define WINDOW 20
#define C4 16  // 64 channels / 4 per float4

typedef float f32x4 __attribute__((ext_vector_type(4)));

__global__ __launch_bounds__(256) void
Pool_46763603919352_kernel(const float* __restrict__ x,
                           const float* __restrict__ y,
                           float* __restrict__ out,
                           int G) {
    int tid = blockIdx.x * blockDim.x + threadIdx.x;
    int total = G * C4;
    if (tid >= total) return;

    int g  = tid >> 4;        // group index
    int c4 = tid & (C4 - 1);  // which float4 within the 64-channel row

    const f32x4* xg = reinterpret_cast<const f32x4*>(x)
                      + (size_t)g * WINDOW * C4 + c4;
    const float* yg = y + (size_t)g * WINDOW;

    f32x4 acc = (f32x4)(0.f);
#pragma unroll
    for (int w = 0; w < WINDOW; ++w) {
        f32x4 v = __builtin_nontemporal_load(&xg[(size_t)w * C4]);
        float s = yg[w];
        acc += v * s;
    }
    __builtin_nontemporal_store(acc, &reinterpret_cast<f32x4*>(out)[tid]);
}

extern "C" void kernel_launch(void* const* d_in, const int* in_sizes, int n_in,
                              void* d_out, int out_size, void* d_ws, size_t ws_size,
                              hipStream_t stream) {
    const float* x = (const float*)d_in[0];
    const float* y = (const float*)d_in[1];
    // d_in[2] = batch (unused on fla==0 path), d_in[3] = fla (always 0 here)
    float* out = (float*)d_out;

    int N = in_sizes[1];        // y has N elements
    int G = N / WINDOW;         // number of output rows

    int total   = G * C4;      // one thread per output float4
    int block   = 256;
    int grid    = (total + block - 1) / block;
    Pool_46763603919352_kernel<<<grid, block, 0, stream>>>(x, y, out, G);
}